// Round 3
// baseline (287.223 us; speedup 1.0000x reference)
//
#include <hip/hip_runtime.h>
#include <hip/hip_bf16.h>

// ---------------- problem constants ----------------
#define B_TOTAL   32768
#define L_SITES   256
#define N_MID     254        // L-2 middle sites
#define HALF_PI_F 1.57079632679489662f
#define EPS_NORM  1e-8f

// ---------------- ws layout (float/dword slots) ----------------
// [WS_FRAG .. +520191]  A-operand fragment table: 254 steps x 8 frags x 64 lanes x 4 dwords
//                       frag q = h*4 + kh*2 + p  (h: c-half, kh: feature, p: 0=hi,1=lo)
//                       contraction axis PI-PERMUTED (k-slot (quad,j) holds
//                       a = (j<4 ? quad*4+j : 16+quad*4+j-4)) so the swapped-MFMA
//                       output feeds the next step with no transpose.
// [WS_C0   .. +63]      core0 fp32  [f][32]
// [WS_CN   .. +639]     coreN fp32  [f][a][10]
// [WS_X    .. +8388607] xT fp32 [L][B]  (transposed)
// [WS_FLAG]             u32 flag: 1 = inputs are bf16, 0 = fp32
#define WS_FRAG 0
#define WS_C0   520192
#define WS_CN   520256
#define WS_X    520896
#define WS_FLAG 8909504

typedef short bf16x8 __attribute__((ext_vector_type(8)));
typedef float f32x4  __attribute__((ext_vector_type(4)));

// pi-permutation of the contraction axis (k-slot -> actual a index)
__device__ __host__ __forceinline__ int pi_perm(int quad, int j) {
    return (j < 4) ? (quad * 4 + j) : (16 + quad * 4 + (j - 4));
}

__device__ __forceinline__ unsigned short f2bf(float f) {
    unsigned u = __builtin_bit_cast(unsigned, f);
    u += 0x7FFFu + ((u >> 16) & 1u);          // RNE
    return (unsigned short)(u >> 16);
}
__device__ __forceinline__ float bf2f(unsigned short h) {
    unsigned u = ((unsigned)h) << 16;
    return __builtin_bit_cast(float, u);
}
__device__ __forceinline__ bf16x8 asbf(uint4 u) {
    return __builtin_bit_cast(bf16x8, u);
}
// packed RNE f32x2 -> bf16x2 (lowers to v_cvt_pk_bf16_f32)
__device__ __forceinline__ unsigned pkbf2(float a, float b) {
    float2 p; p.x = a; p.y = b;
    __hip_bfloat162 h2 = __float22bfloat162_rn(p);
    unsigned u;
    __builtin_memcpy(&u, &h2, 4);
    return u;                                  // a in bits 0..15, b in 16..31
}
// split 8 fp32 into hi/lo bf16 fragments via packed cvt (RNE, proven)
__device__ __forceinline__ void split8(const float* v, bf16x8& hi, bf16x8& lo) {
    uint4 H, L;
    unsigned* hp = (unsigned*)&H;
    unsigned* lp = (unsigned*)&L;
    #pragma unroll
    for (int d = 0; d < 4; ++d) {
        float a = v[2 * d], b = v[2 * d + 1];
        unsigned hb = pkbf2(a, b);
        float h0 = __builtin_bit_cast(float, hb << 16);
        float h1 = __builtin_bit_cast(float, hb & 0xFFFF0000u);
        hp[d] = hb;
        lp[d] = pkbf2(a - h0, b - h1);         // exact residuals
    }
    hi = __builtin_bit_cast(bf16x8, H);
    lo = __builtin_bit_cast(bf16x8, L);
}
// per-wave input-dtype flag: bf16 pairs always have low16 < 0x4000
__device__ __forceinline__ bool detect_bf16(const unsigned* x_raw, int lane) {
    unsigned v = x_raw[lane];
    return __ballot((v & 0xFFFFu) >= 0x4000u) == 0ull;
}
// async global -> LDS DMA, 16 B/lane (dest = wave-uniform base + lane*16)
__device__ __forceinline__ void dma16(const uint4* g, uint4* l) {
    __builtin_amdgcn_global_load_lds(
        (const __attribute__((address_space(1))) unsigned*)g,
        (__attribute__((address_space(3))) unsigned*)l, 16, 0, 0);
}

// ---------------- fused aux kernel ----------------
// blocks [0,2048)   : x transpose [B][L] -> xT [L][B] fp32 (VECTORIZED this round)
// blocks [2048,2556): A-fragment builder (pi-permuted contraction axis)
// block  2556       : small cores -> fp32, + WS_FLAG write
__global__ __launch_bounds__(256)
void aux_all(const void* __restrict__ x_in, const void* __restrict__ c0_in,
             const void* __restrict__ am_in, const void* __restrict__ cn_in,
             float* __restrict__ ws) {
    const int lane = threadIdx.x & 63;
    const bool bf = detect_bf16((const unsigned*)x_in, lane);
    const int b = blockIdx.x;

    if (b < 2048) {
        __shared__ float tile[64][65];          // tile[b_local][l_local], +1 pad
        const int bb = (b & 511) * 64;
        const int ll = (b >> 9) * 64;
        const int row = threadIdx.x >> 2;       // 0..63  (b_local)
        const int q   = threadIdx.x & 3;        // 0..3
        if (!bf) {
            const float4* x4 = (const float4*)x_in;   // [B][64] float4 per row
            #pragma unroll
            for (int u = 0; u < 4; ++u) {
                int c4 = q + u * 4;             // 16 float4 per row / 4 lanes... x4 idx
                float4 v = x4[(size_t)(bb + row) * (L_SITES / 4) + (ll / 4) + c4];
                tile[row][c4 * 4 + 0] = v.x;
                tile[row][c4 * 4 + 1] = v.y;
                tile[row][c4 * 4 + 2] = v.z;
                tile[row][c4 * 4 + 3] = v.w;
            }
        } else {
            const uint4* x4 = (const uint4*)x_in;     // [B][32] uint4 (8 bf16 each)
            #pragma unroll
            for (int u = 0; u < 2; ++u) {
                int c8 = q + u * 4;             // 8 uint4 of this 64-col slice
                uint4 v = x4[(size_t)(bb + row) * (L_SITES / 8) + (ll / 8) + c8];
                const unsigned short* e = (const unsigned short*)&v;
                #pragma unroll
                for (int k = 0; k < 8; ++k) tile[row][c8 * 8 + k] = bf2f(e[k]);
            }
        }
        __syncthreads();
        // write: float4 along B.  thread: lrow = tid>>2, bq = tid&3 (+u*4)
        const int lrow = threadIdx.x >> 2;
        const int bq   = threadIdx.x & 3;
        float4* o4 = (float4*)(ws + WS_X);
        #pragma unroll
        for (int u = 0; u < 4; ++u) {
            int b4 = bq + u * 4;                // float4 index within 64-col B slice
            float4 v;
            v.x = tile[b4 * 4 + 0][lrow];
            v.y = tile[b4 * 4 + 1][lrow];
            v.z = tile[b4 * 4 + 2][lrow];
            v.w = tile[b4 * 4 + 3][lrow];
            o4[((size_t)(ll + lrow) * B_TOTAL + bb) / 4 + b4] = v;
        }
    } else if (b < 2556) {
        int i = (b - 2048) * 256 + threadIdx.x;
        if (i < N_MID * 8 * 64) {
            const int l  = i & 63;
            const int q  = (i >> 6) & 7;
            const int t  = i >> 9;
            const int h  = q >> 2;
            const int kh = (q >> 1) & 1;
            const int p  = q & 1;
            const int m  = h * 16 + (l & 15);      // output-c index (A-operand row)
            const int kb = (l >> 4) * 8;           // k-slot base for this lane's quad
            unsigned dw[4];
            #pragma unroll
            for (int d = 0; d < 4; ++d) {
                unsigned e01[2];
                #pragma unroll
                for (int s = 0; s < 2; ++s) {
                    int k  = kb + 2 * d + s;       // k-slot 0..31
                    int a  = pi_perm(k >> 3, k & 7); // PI-permuted contraction index
                    size_t idx = ((size_t)(t * 2 + kh) * 32 + a) * 32 + m;
                    float v = bf ? bf2f(((const unsigned short*)am_in)[idx])
                                 : ((const float*)am_in)[idx];
                    unsigned short hi = f2bf(v);
                    e01[s] = (p == 0) ? hi : f2bf(v - bf2f(hi));
                }
                dw[d] = e01[0] | (e01[1] << 16);
            }
            uint4 o; o.x = dw[0]; o.y = dw[1]; o.z = dw[2]; o.w = dw[3];
            ((uint4*)ws)[(size_t)(t * 8 + q) * 64 + l] = o;
        }
    } else {
        for (int i = threadIdx.x; i < 640; i += 256) {
            if (i < 64)
                ws[WS_C0 + i] = bf ? bf2f(((const unsigned short*)c0_in)[i])
                                   : ((const float*)c0_in)[i];
            ws[WS_CN + i] = bf ? bf2f(((const unsigned short*)cn_in)[i])
                               : ((const float*)cn_in)[i];
        }
        if (threadIdx.x == 0)
            *(unsigned*)(ws + WS_FLAG) = bf ? 1u : 0u;
    }
}

// ---------------- main chain kernel ----------------
// Round-2 swapped-operand register chain (no transpose) +
// THIS ROUND: cooperative fragment staging. The 4 waves of a block DMA the
// step's 8 KB fragment chunk into LDS ONCE (global_load_lds, 2 KB per wave,
// issued 2 steps ahead into a 3-buffer ring) instead of each wave issuing 8
// redundant 1 KB gathers -> 4x fewer VMEM transactions per CU. Consumption is
// contiguous ds_read_b128 (conflict-free). Per-iter sync = explicit
// s_waitcnt vmcnt(0) + raw s_barrier (NOT __syncthreads: avoids the
// compiler's full-drain stall; the waited loads were issued a full step
// earlier and have landed). In-loop VMEM = 2 DMA + 1 x-load per wave only.
// Numerics bit-identical to round 2.
__global__ __launch_bounds__(256)
void mps_mfma(const float* __restrict__ ws, const void* __restrict__ x_in,
              void* __restrict__ out) {
    __shared__ uint4 FR[3][512];                // 3 x 8 KB step buffers
    const int lane = threadIdx.x & 63;
    const int w    = threadIdx.x >> 6;
    const int r    = lane & 15;
    const int quad = lane >> 4;
    const int b0   = (blockIdx.x * 4 + w) * 16;
    const float* __restrict__ xT = ws + WS_X;
    const uint4* __restrict__ BF = (const uint4*)ws;   // WS_FRAG = 0
    const int i = b0 + r;
    const bool bf = detect_bf16((const unsigned*)x_in, lane);

    // ---- prologue DMAs: step 0 -> FR[0], step 1 -> FR[1] (wave w: frags 2w,2w+1)
    {
        const uint4* S0 = BF + (size_t)(0 * 8 + 2 * w) * 64 + lane;
        dma16(S0,       &FR[0][w * 128]);
        dma16(S0 + 64,  &FR[0][w * 128 + 64]);
        const uint4* S1 = BF + (size_t)(1 * 8 + 2 * w) * 64 + lane;
        dma16(S1,       &FR[1][w * 128]);
        dma16(S1 + 64,  &FR[1][w * 128 + 64]);
    }

    // ---- M0 in pi-layout: mm[j] = M0[b=r][a=pi(quad,j)] ----
    float mm[8];
    {
        float x0 = xT[i];
        float sn, cs; __sincosf(HALF_PI_F * x0, &sn, &cs);
        const float* c0 = ws + WS_C0;
        #pragma unroll
        for (int j = 0; j < 8; ++j) {
            int a = pi_perm(quad, j);
            mm[j] = cs * c0[a] + sn * c0[32 + a];
        }
    }

    // ---- x / sincos pipeline prologue ----
    float ct, st;
    { float xc = xT[(size_t)B_TOTAL + i]; __sincosf(HALF_PI_F * xc, &st, &ct); }
    float xn = xT[(size_t)2 * B_TOTAL + i];            // x of step 1 (site 2)

    __syncthreads();   // x staging none, but drains prologue DMAs + aligns waves

    int cur = 0;
    #pragma unroll 1
    for (int t = 0; t < N_MID; ++t) {
        // ---- sync: my DMAs from >=1 iter ago have landed; all waves aligned ----
        asm volatile("s_waitcnt vmcnt(0)" ::: "memory");
        __builtin_amdgcn_s_barrier();
        asm volatile("" ::: "memory");

        // ---- DMA step t+2 into ring buffer (t+2)%3 == (cur+2)%3 ----
        {
            int n2 = (cur == 0) ? 2 : cur - 1;
            const uint4* S = BF + ((size_t)(t + 2) * 8 + 2 * w) * 64 + lane;
            dma16(S,      &FR[n2][w * 128]);
            dma16(S + 64, &FR[n2][w * 128 + 64]);
        }

        // ---- fragments for step t from LDS (contiguous b128, conflict-free) ----
        const uint4* F = &FR[cur][0];
        uint4 f0 = F[lane];        uint4 f1 = F[64 + lane];
        uint4 f2 = F[128 + lane];  uint4 f3 = F[192 + lane];
        uint4 f4 = F[256 + lane];  uint4 f5 = F[320 + lane];
        uint4 f6 = F[384 + lane];  uint4 f7 = F[448 + lane];

        // ---- next-step scale factors + x prefetch (off critical path) ----
        float ctn, stn; __sincosf(HALF_PI_F * xn, &stn, &ctn);
        int xr = t + 3; if (xr > 255) xr = 255;
        float xn2 = xT[(size_t)xr * B_TOTAL + i];

        // ---- chain step: scale -> split -> 12 MFMA (2 indep 6-chains) ----
        float s0[8], s1[8];
        #pragma unroll
        for (int j = 0; j < 8; ++j) { s0[j] = ct * mm[j]; s1[j] = st * mm[j]; }
        bf16x8 b0h, b0l, b1h, b1l;
        split8(s0, b0h, b0l);
        split8(s1, b1h, b1l);
        const f32x4 z = {0.f, 0.f, 0.f, 0.f};
        __builtin_amdgcn_s_setprio(1);
        f32x4 a0 = __builtin_amdgcn_mfma_f32_16x16x32_bf16(asbf(f0), b0h, z, 0, 0, 0);
        f32x4 a1 = __builtin_amdgcn_mfma_f32_16x16x32_bf16(asbf(f4), b0h, z, 0, 0, 0);
        a0 = __builtin_amdgcn_mfma_f32_16x16x32_bf16(asbf(f1), b0h, a0, 0, 0, 0);
        a1 = __builtin_amdgcn_mfma_f32_16x16x32_bf16(asbf(f5), b0h, a1, 0, 0, 0);
        a0 = __builtin_amdgcn_mfma_f32_16x16x32_bf16(asbf(f0), b0l, a0, 0, 0, 0);
        a1 = __builtin_amdgcn_mfma_f32_16x16x32_bf16(asbf(f4), b0l, a1, 0, 0, 0);
        a0 = __builtin_amdgcn_mfma_f32_16x16x32_bf16(asbf(f2), b1h, a0, 0, 0, 0);
        a1 = __builtin_amdgcn_mfma_f32_16x16x32_bf16(asbf(f6), b1h, a1, 0, 0, 0);
        a0 = __builtin_amdgcn_mfma_f32_16x16x32_bf16(asbf(f3), b1h, a0, 0, 0, 0);
        a1 = __builtin_amdgcn_mfma_f32_16x16x32_bf16(asbf(f7), b1h, a1, 0, 0, 0);
        a0 = __builtin_amdgcn_mfma_f32_16x16x32_bf16(asbf(f2), b1l, a0, 0, 0, 0);
        a1 = __builtin_amdgcn_mfma_f32_16x16x32_bf16(asbf(f6), b1l, a1, 0, 0, 0);
        __builtin_amdgcn_s_setprio(0);
        mm[0] = a0[0]; mm[1] = a0[1]; mm[2] = a0[2]; mm[3] = a0[3];
        mm[4] = a1[0]; mm[5] = a1[1]; mm[6] = a1[2]; mm[7] = a1[3];

        // ---- normalize every 8th step + final (scale cancels in between) ----
        if (((t & 7) == 7) || (t == N_MID - 1)) {
            float ss = 0.f;
            #pragma unroll
            for (int j = 0; j < 8; ++j) ss = fmaf(mm[j], mm[j], ss);
            ss += __shfl_xor(ss, 16);
            ss += __shfl_xor(ss, 32);
            float kk = 1.0f / (sqrtf(ss) + EPS_NORM);
            #pragma unroll
            for (int j = 0; j < 8; ++j) mm[j] *= kk;
        }

        ct = ctn; st = stn; xn = xn2;
        if (++cur == 3) cur = 0;
    }

    // ---- readout: logits[r][c] = sum_a M[r][a]*(cN*KN0[a,c] + sN*KN1[a,c]) ----
    {
        float xN = xT[(size_t)(L_SITES - 1) * B_TOTAL + i];
        float sN, cN; __sincosf(HALF_PI_F * xN, &sN, &cN);
        const float* kn = ws + WS_CN;        // [f][a][10]
        float acc[10];
        #pragma unroll
        for (int c = 0; c < 10; ++c) acc[c] = 0.f;
        #pragma unroll
        for (int j = 0; j < 8; ++j) {
            int a = pi_perm(quad, j);
            float Ma = mm[j];
            #pragma unroll
            for (int c = 0; c < 10; ++c) {
                float fin = cN * kn[a * 10 + c] + sN * kn[320 + a * 10 + c];
                acc[c] = fmaf(Ma, fin, acc[c]);
            }
        }
        #pragma unroll
        for (int c = 0; c < 10; ++c) {
            acc[c] += __shfl_xor(acc[c], 16);
            acc[c] += __shfl_xor(acc[c], 32);
        }
        if (quad == 0) {
            if (bf) {
                __hip_bfloat16* o = (__hip_bfloat16*)out;
                #pragma unroll
                for (int c = 0; c < 10; ++c)
                    o[(size_t)(b0 + r) * 10 + c] = __float2bfloat16(acc[c]);
            } else {
                float* o = (float*)out;
                #pragma unroll
                for (int c = 0; c < 10; ++c)
                    o[(size_t)(b0 + r) * 10 + c] = acc[c];
            }
        }
    }
}

// ---------------- launch ----------------
extern "C" void kernel_launch(void* const* d_in, const int* in_sizes, int n_in,
                              void* d_out, int out_size, void* d_ws, size_t ws_size,
                              hipStream_t stream) {
    float* ws = (float*)d_ws;
    aux_all<<<2557, 256, 0, stream>>>(d_in[0], d_in[1], d_in[2], d_in[3], ws);
    // 512 blocks x 4 waves x 16 samples = 32768 samples; 2048 waves = 2 waves/SIMD
    mps_mfma<<<512, 256, 0, stream>>>(ws, d_in[0], d_out);
}

// Round 4
// 232.902 us; speedup vs baseline: 1.2332x; 1.2332x over previous
//
#include <hip/hip_runtime.h>
#include <hip/hip_bf16.h>

// ---------------- problem constants ----------------
#define B_TOTAL   32768
#define L_SITES   256
#define N_MID     254        // L-2 middle sites
#define HALF_PI_F 1.57079632679489662f
#define EPS_NORM  1e-8f

// ---------------- ws layout (float/dword slots) ----------------
// [WS_FRAG .. +520191]  A-operand fragment table: 254 steps x 8 frags x 64 lanes x 4 dwords
//                       frag q = h*4 + kh*2 + p  (h: c-half, kh: feature, p: 0=hi,1=lo)
//                       contraction axis PI-PERMUTED (k-slot (quad,j) holds
//                       a = (j<4 ? quad*4+j : 16+quad*4+j-4)) so the swapped-MFMA
//                       output feeds the next step with no transpose.
// [WS_C0   .. +63]      core0 fp32  [f][32]
// [WS_CN   .. +639]     coreN fp32  [f][a][10]
// [WS_X    .. +8388607] xT fp32 [L][B]  (transposed)
// [WS_FLAG]             u32 flag: 1 = inputs are bf16, 0 = fp32
#define WS_FRAG 0
#define WS_C0   520192
#define WS_CN   520256
#define WS_X    520896
#define WS_FLAG 8909504

typedef short bf16x8 __attribute__((ext_vector_type(8)));
typedef float f32x4  __attribute__((ext_vector_type(4)));

// pi-permutation of the contraction axis (k-slot -> actual a index)
__device__ __host__ __forceinline__ int pi_perm(int quad, int j) {
    return (j < 4) ? (quad * 4 + j) : (16 + quad * 4 + (j - 4));
}

__device__ __forceinline__ unsigned short f2bf(float f) {
    unsigned u = __builtin_bit_cast(unsigned, f);
    u += 0x7FFFu + ((u >> 16) & 1u);          // RNE
    return (unsigned short)(u >> 16);
}
__device__ __forceinline__ float bf2f(unsigned short h) {
    unsigned u = ((unsigned)h) << 16;
    return __builtin_bit_cast(float, u);
}
__device__ __forceinline__ bf16x8 asbf(uint4 u) {
    return __builtin_bit_cast(bf16x8, u);
}
// packed RNE f32x2 -> bf16x2 (lowers to v_cvt_pk_bf16_f32)
__device__ __forceinline__ unsigned pkbf2(float a, float b) {
    float2 p; p.x = a; p.y = b;
    __hip_bfloat162 h2 = __float22bfloat162_rn(p);
    unsigned u;
    __builtin_memcpy(&u, &h2, 4);
    return u;                                  // a in bits 0..15, b in 16..31
}
// split 8 fp32 into hi/lo bf16 fragments via packed cvt (RNE, proven)
__device__ __forceinline__ void split8(const float* v, bf16x8& hi, bf16x8& lo) {
    uint4 H, L;
    unsigned* hp = (unsigned*)&H;
    unsigned* lp = (unsigned*)&L;
    #pragma unroll
    for (int d = 0; d < 4; ++d) {
        float a = v[2 * d], b = v[2 * d + 1];
        unsigned hb = pkbf2(a, b);
        float h0 = __builtin_bit_cast(float, hb << 16);
        float h1 = __builtin_bit_cast(float, hb & 0xFFFF0000u);
        hp[d] = hb;
        lp[d] = pkbf2(a - h0, b - h1);         // exact residuals
    }
    hi = __builtin_bit_cast(bf16x8, H);
    lo = __builtin_bit_cast(bf16x8, L);
}
// per-wave input-dtype flag: bf16 pairs always have low16 < 0x4000
__device__ __forceinline__ bool detect_bf16(const unsigned* x_raw, int lane) {
    unsigned v = x_raw[lane];
    return __ballot((v & 0xFFFFu) >= 0x4000u) == 0ull;
}

// ---------------- fused aux kernel ----------------
// blocks [0,2048)   : x transpose [B][L] -> xT [L][B] fp32 (vectorized, 256B rows)
// blocks [2048,2556): A-fragment builder (pi-permuted contraction axis)
// block  2556       : small cores -> fp32, + WS_FLAG write
__global__ __launch_bounds__(256)
void aux_all(const void* __restrict__ x_in, const void* __restrict__ c0_in,
             const void* __restrict__ am_in, const void* __restrict__ cn_in,
             float* __restrict__ ws) {
    const int lane = threadIdx.x & 63;
    const bool bf = detect_bf16((const unsigned*)x_in, lane);
    const int b = blockIdx.x;

    if (b < 2048) {
        __shared__ float tile[64][65];          // tile[b_local][l_local], +1 pad
        const int bb = (b & 511) * 64;
        const int ll = (b >> 9) * 64;
        if (!bf) {
            // 16 threads per row: 256 B contiguous reads
            const float4* x4 = (const float4*)x_in;   // row = 64 float4
            const int tr = threadIdx.x >> 4;    // 0..15
            const int q  = threadIdx.x & 15;    // 0..15
            #pragma unroll
            for (int u = 0; u < 4; ++u) {
                int row = tr + u * 16;
                float4 v = x4[(size_t)(bb + row) * (L_SITES / 4) + (ll / 4) + q];
                tile[row][q * 4 + 0] = v.x;
                tile[row][q * 4 + 1] = v.y;
                tile[row][q * 4 + 2] = v.z;
                tile[row][q * 4 + 3] = v.w;
            }
        } else {
            // 8 threads per row: 128 B contiguous reads
            const uint4* x8 = (const uint4*)x_in;     // row = 32 uint4 (8 bf16 each)
            const int tr = threadIdx.x >> 3;    // 0..31
            const int q  = threadIdx.x & 7;     // 0..7
            #pragma unroll
            for (int u = 0; u < 2; ++u) {
                int row = tr + u * 32;
                uint4 v = x8[(size_t)(bb + row) * (L_SITES / 8) + (ll / 8) + q];
                const unsigned short* e = (const unsigned short*)&v;
                #pragma unroll
                for (int k = 0; k < 8; ++k) tile[row][q * 8 + k] = bf2f(e[k]);
            }
        }
        __syncthreads();
        // write: 16 threads per site-row -> 256 B contiguous stores along B
        {
            const int tr = threadIdx.x >> 4;    // 0..15
            const int q  = threadIdx.x & 15;    // 0..15
            float4* o4 = (float4*)(ws + WS_X);
            #pragma unroll
            for (int u = 0; u < 4; ++u) {
                int site = tr + u * 16;         // l_local
                float4 v;
                v.x = tile[q * 4 + 0][site];
                v.y = tile[q * 4 + 1][site];
                v.z = tile[q * 4 + 2][site];
                v.w = tile[q * 4 + 3][site];
                o4[((size_t)(ll + site) * B_TOTAL + bb) / 4 + q] = v;
            }
        }
    } else if (b < 2556) {
        int i = (b - 2048) * 256 + threadIdx.x;
        if (i < N_MID * 8 * 64) {
            const int l  = i & 63;
            const int q  = (i >> 6) & 7;
            const int t  = i >> 9;
            const int h  = q >> 2;
            const int kh = (q >> 1) & 1;
            const int p  = q & 1;
            const int m  = h * 16 + (l & 15);      // output-c index (A-operand row)
            const int kb = (l >> 4) * 8;           // k-slot base for this lane's quad
            unsigned dw[4];
            #pragma unroll
            for (int d = 0; d < 4; ++d) {
                unsigned e01[2];
                #pragma unroll
                for (int s = 0; s < 2; ++s) {
                    int k  = kb + 2 * d + s;       // k-slot 0..31
                    int a  = pi_perm(k >> 3, k & 7); // PI-permuted contraction index
                    size_t idx = ((size_t)(t * 2 + kh) * 32 + a) * 32 + m;
                    float v = bf ? bf2f(((const unsigned short*)am_in)[idx])
                                 : ((const float*)am_in)[idx];
                    unsigned short hi = f2bf(v);
                    e01[s] = (p == 0) ? hi : f2bf(v - bf2f(hi));
                }
                dw[d] = e01[0] | (e01[1] << 16);
            }
            uint4 o; o.x = dw[0]; o.y = dw[1]; o.z = dw[2]; o.w = dw[3];
            ((uint4*)ws)[(size_t)(t * 8 + q) * 64 + l] = o;
        }
    } else {
        for (int i = threadIdx.x; i < 640; i += 256) {
            if (i < 64)
                ws[WS_C0 + i] = bf ? bf2f(((const unsigned short*)c0_in)[i])
                                   : ((const float*)c0_in)[i];
            ws[WS_CN + i] = bf ? bf2f(((const unsigned short*)cn_in)[i])
                               : ((const float*)cn_in)[i];
        }
        if (threadIdx.x == 0)
            *(unsigned*)(ws + WS_FLAG) = bf ? 1u : 0u;
    }
}

// ---------------- main chain kernel ----------------
// Round-2 skeleton (independent waves, register ping-pong prefetch, no LDS,
// no barriers — round-3's cooperative staging regressed and is reverted).
// THIS ROUND: post-scale factorization. Instead of splitting ct*M and st*M
// (2 splits + 16 muls, two 6-deep MFMA chains), split M ONCE and compute the
// two feature products separately, then combine: M' = ct*(A0^T M) + st*(A1^T M).
// Valid because ct/st are per-sample and output C-columns are samples (same
// lane). Gains: ~40 fewer VALU ops/step on the chain; 4 independent 3-deep
// MFMA chains (half the exposed dependent latency); sincos needed only at the
// combine (fully hidden). Same 12 MFMAs, same 3 split terms per feature
// (lo*lo term dropped as before).
__global__ __launch_bounds__(256)
void mps_mfma(const float* __restrict__ ws, void* __restrict__ out) {
    const int lane = threadIdx.x & 63;
    const int w    = threadIdx.x >> 6;
    const int r    = lane & 15;
    const int quad = lane >> 4;
    const int b0   = (blockIdx.x * 4 + w) * 16;
    const float* __restrict__ xT = ws + WS_X;
    const uint4* __restrict__ BF = (const uint4*)ws;   // WS_FRAG = 0
    const int i = b0 + r;

    // ---- M0 in pi-layout: mm[j] = M0[b=r][a=pi(quad,j)] ----
    float mm[8];
    {
        float x0 = xT[i];
        float sn, cs; __sincosf(HALF_PI_F * x0, &sn, &cs);
        const float* c0 = ws + WS_C0;
        #pragma unroll
        for (int j = 0; j < 8; ++j) {
            int a = pi_perm(quad, j);
            mm[j] = cs * c0[a] + sn * c0[32 + a];
        }
    }

// one chain step: split M once -> 12 MFMA (4 indep 3-chains) -> post-scale
// combine with (CT,ST) -> optional norm.
// Qq roles: Q0=(h0,f0,hi) Q1=(h0,f0,lo) Q2=(h0,f1,hi) Q3=(h0,f1,lo)
//           Q4=(h1,f0,hi) Q5=(h1,f0,lo) Q6=(h1,f1,hi) Q7=(h1,f1,lo)
#define DO_STEP(CT, ST, Q0, Q1, Q2, Q3, Q4, Q5, Q6, Q7, DONORM)                    \
    {                                                                              \
        bf16x8 mh, ml;                                                             \
        split8(mm, mh, ml);                                                        \
        const f32x4 z = {0.f, 0.f, 0.f, 0.f};                                      \
        __builtin_amdgcn_s_setprio(1);                                             \
        f32x4 p00 = __builtin_amdgcn_mfma_f32_16x16x32_bf16(asbf(Q0), mh, z, 0, 0, 0);    \
        f32x4 p01 = __builtin_amdgcn_mfma_f32_16x16x32_bf16(asbf(Q2), mh, z, 0, 0, 0);    \
        f32x4 p10 = __builtin_amdgcn_mfma_f32_16x16x32_bf16(asbf(Q4), mh, z, 0, 0, 0);    \
        f32x4 p11 = __builtin_amdgcn_mfma_f32_16x16x32_bf16(asbf(Q6), mh, z, 0, 0, 0);    \
        p00 = __builtin_amdgcn_mfma_f32_16x16x32_bf16(asbf(Q1), mh, p00, 0, 0, 0); \
        p01 = __builtin_amdgcn_mfma_f32_16x16x32_bf16(asbf(Q3), mh, p01, 0, 0, 0); \
        p10 = __builtin_amdgcn_mfma_f32_16x16x32_bf16(asbf(Q5), mh, p10, 0, 0, 0); \
        p11 = __builtin_amdgcn_mfma_f32_16x16x32_bf16(asbf(Q7), mh, p11, 0, 0, 0); \
        p00 = __builtin_amdgcn_mfma_f32_16x16x32_bf16(asbf(Q0), ml, p00, 0, 0, 0); \
        p01 = __builtin_amdgcn_mfma_f32_16x16x32_bf16(asbf(Q2), ml, p01, 0, 0, 0); \
        p10 = __builtin_amdgcn_mfma_f32_16x16x32_bf16(asbf(Q4), ml, p10, 0, 0, 0); \
        p11 = __builtin_amdgcn_mfma_f32_16x16x32_bf16(asbf(Q6), ml, p11, 0, 0, 0); \
        __builtin_amdgcn_s_setprio(0);                                             \
        _Pragma("unroll")                                                          \
        for (int j = 0; j < 4; ++j) {                                              \
            mm[j]     = fmaf((ST), p01[j], (CT) * p00[j]);                         \
            mm[4 + j] = fmaf((ST), p11[j], (CT) * p10[j]);                         \
        }                                                                          \
        if (DONORM) {                                                              \
            float ss = 0.f;                                                        \
            _Pragma("unroll")                                                      \
            for (int j = 0; j < 8; ++j) ss = fmaf(mm[j], mm[j], ss);               \
            ss += __shfl_xor(ss, 16);                                              \
            ss += __shfl_xor(ss, 32);                                              \
            float kk = 1.0f / (sqrtf(ss) + EPS_NORM);                              \
            _Pragma("unroll")                                                      \
            for (int j = 0; j < 8; ++j) mm[j] *= kk;                               \
        }                                                                          \
    }

    // ---- pipeline prologue ----
    float ct0, st0;
    { float xc = xT[(size_t)B_TOTAL + i]; __sincosf(HALF_PI_F * xc, &st0, &ct0); }
    float x1 = xT[(size_t)2 * B_TOTAL + i];            // x of step 1

    const uint4* Ba = BF + lane;
    uint4 fa0 = Ba[0],   fa1 = Ba[64],  fa2 = Ba[128], fa3 = Ba[192];
    uint4 fa4 = Ba[256], fa5 = Ba[320], fa6 = Ba[384], fa7 = Ba[448];

    #pragma unroll 1
    for (int t = 0; t < N_MID; t += 2) {
        // ======== even step t: consumes (ct0,st0) + fa*; prefetch for t+1 ========
        const uint4* Bb = BF + (size_t)(t + 1) * 512 + lane;       // t+1 <= 253: valid
        uint4 fb0 = Bb[0],   fb1 = Bb[64],  fb2 = Bb[128], fb3 = Bb[192];
        uint4 fb4 = Bb[256], fb5 = Bb[320], fb6 = Bb[384], fb7 = Bb[448];
        float x2 = xT[(size_t)(t + 3) * B_TOTAL + i];              // x of step t+2 (t+3 <= 255)
        float ct1, st1; __sincosf(HALF_PI_F * x1, &st1, &ct1);     // factors for step t+1

        DO_STEP(ct0, st0, fa0, fa1, fa2, fa3, fa4, fa5, fa6, fa7, false)

        // ======== odd step t+1: consumes (ct1,st1) + fb*; prefetch for t+2 ========
        const uint4* Bc = BF + (size_t)(t + 2) * 512 + lane;       // t=252 -> in-ws garbage, never consumed
        fa0 = Bc[0];   fa1 = Bc[64];  fa2 = Bc[128]; fa3 = Bc[192];
        fa4 = Bc[256]; fa5 = Bc[320]; fa6 = Bc[384]; fa7 = Bc[448];
        int xr = t + 4; if (xr > 255) xr = 255;                    // clamp (t=252 -> 256)
        x1 = xT[(size_t)xr * B_TOTAL + i];                         // x of step t+3
        __sincosf(HALF_PI_F * x2, &st0, &ct0);                     // factors for step t+2

        DO_STEP(ct1, st1, fb0, fb1, fb2, fb3, fb4, fb5, fb6, fb7,
                (((t + 1) & 7) == 7) || (t + 1 == N_MID - 1))
    }
#undef DO_STEP

    // ---- readout: logits[r][c] = sum_a M[r][a]*(cN*KN0[a,c] + sN*KN1[a,c]) ----
    {
        float xN = xT[(size_t)(L_SITES - 1) * B_TOTAL + i];
        float sN, cN; __sincosf(HALF_PI_F * xN, &sN, &cN);
        const float* kn = ws + WS_CN;        // [f][a][10]
        float acc[10];
        #pragma unroll
        for (int c = 0; c < 10; ++c) acc[c] = 0.f;
        #pragma unroll
        for (int j = 0; j < 8; ++j) {
            int a = pi_perm(quad, j);
            float Ma = mm[j];
            #pragma unroll
            for (int c = 0; c < 10; ++c) {
                float fin = cN * kn[a * 10 + c] + sN * kn[320 + a * 10 + c];
                acc[c] = fmaf(Ma, fin, acc[c]);
            }
        }
        #pragma unroll
        for (int c = 0; c < 10; ++c) {
            acc[c] += __shfl_xor(acc[c], 16);
            acc[c] += __shfl_xor(acc[c], 32);
        }
        const unsigned bf = *(const unsigned*)(ws + WS_FLAG);
        if (quad == 0) {
            if (bf) {
                __hip_bfloat16* o = (__hip_bfloat16*)out;
                #pragma unroll
                for (int c = 0; c < 10; ++c)
                    o[(size_t)(b0 + r) * 10 + c] = __float2bfloat16(acc[c]);
            } else {
                float* o = (float*)out;
                #pragma unroll
                for (int c = 0; c < 10; ++c)
                    o[(size_t)(b0 + r) * 10 + c] = acc[c];
            }
        }
    }
}

// ---------------- launch ----------------
extern "C" void kernel_launch(void* const* d_in, const int* in_sizes, int n_in,
                              void* d_out, int out_size, void* d_ws, size_t ws_size,
                              hipStream_t stream) {
    float* ws = (float*)d_ws;
    aux_all<<<2557, 256, 0, stream>>>(d_in[0], d_in[1], d_in[2], d_in[3], ws);
    // 512 blocks x 4 waves x 16 samples = 32768 samples; 2048 waves = 2 waves/SIMD
    mps_mfma<<<512, 256, 0, stream>>>(ws, d_out);
}